// Round 1
// baseline (1063.102 us; speedup 1.0000x reference)
//
#include <hip/hip_runtime.h>

// GCN encoder: 3 layers, out = D^-1/2 (A+I) D^-1/2 X W + b, relu between.
// Factored: g = (X W) * dinv[row];  out[d] = dinv[d]*(sum_{s->d} g[s] + g[d]) + b

__global__ void k_init_deg(float* deg, int n) {
    int i = blockIdx.x * blockDim.x + threadIdx.x;
    if (i < n) deg[i] = 1.0f;  // self-loop contributes 1
}

__global__ void k_edge_deg(const int* __restrict__ dst, float* deg, int e) {
    int i = blockIdx.x * blockDim.x + threadIdx.x;
    if (i < e) atomicAdd(&deg[dst[i]], 1.0f);
}

__global__ void k_dinv(float* deg, int n) {
    int i = blockIdx.x * blockDim.x + threadIdx.x;
    if (i < n) deg[i] = 1.0f / sqrtf(deg[i]);  // deg >= 1 always
}

// g[node][f] = dinv[node] * sum_k in[node][k] * W[k][f]
// Block 256 threads. Each thread computes 4 consecutive output dims for one node.
template <int K, int F>
__global__ __launch_bounds__(256) void k_gemm_scale(
    const float* __restrict__ in, const float* __restrict__ W,
    const float* __restrict__ dinv, float* __restrict__ g, int n) {
    constexpr int F4 = F / 4;       // threads per node
    constexpr int T  = 256 / F4;    // nodes per block
    __shared__ float Ws[K * F];
    __shared__ float xs[T][K + 4];  // +4 pad: breaks pow2 stride, keeps 16B align
    const int tid = threadIdx.x;

    for (int i = tid; i < K * F; i += 256) Ws[i] = W[i];
    const int node0 = blockIdx.x * T;
    for (int i = tid; i < T * K; i += 256) {
        int r = i / K, c = i % K;   // K is pow2 -> cheap
        xs[r][c] = in[(node0 + r) * K + c];
    }
    __syncthreads();

    const int nl = tid / F4;
    const int fq = tid % F4;
    float4 acc = {0.f, 0.f, 0.f, 0.f};
    const float4* Wv = reinterpret_cast<const float4*>(Ws);
#pragma unroll 8
    for (int k = 0; k < K; ++k) {
        float  xv = xs[nl][k];
        float4 w  = Wv[k * F4 + fq];
        acc.x += xv * w.x; acc.y += xv * w.y;
        acc.z += xv * w.z; acc.w += xv * w.w;
    }
    const int node = node0 + nl;
    const float dv = dinv[node];
    float4 r = {acc.x * dv, acc.y * dv, acc.z * dv, acc.w * dv};
    *reinterpret_cast<float4*>(&g[node * F + fq * 4]) = r;
}

// acc[dst][f] += g[src][f] over all edges. One thread per (edge, dim).
template <int F>
__global__ __launch_bounds__(256) void k_scatter(
    const float* __restrict__ g, const int* __restrict__ src,
    const int* __restrict__ dst, float* __restrict__ acc, int e) {
    int gid  = blockIdx.x * 256 + threadIdx.x;
    int eidx = gid / F;
    int f    = gid % F;
    if (eidx < e) {
        int s = src[eidx], d = dst[eidx];
        atomicAdd(&acc[d * F + f], g[s * F + f]);
    }
}

// out[n][f] = (relu?)( dinv[n]*(acc[n][f] + g[n][f]) + b[f] )
template <int F, bool RELU>
__global__ __launch_bounds__(256) void k_finalize(
    const float* __restrict__ acc, const float* __restrict__ g,
    const float* __restrict__ dinv, const float* __restrict__ b,
    float* __restrict__ out, int n) {
    int gid = blockIdx.x * 256 + threadIdx.x;
    int node = gid / F, f = gid % F;
    if (node < n) {
        float v = dinv[node] * (acc[gid] + g[gid]) + b[f];
        if (RELU) v = fmaxf(v, 0.f);
        out[gid] = v;
    }
}

extern "C" void kernel_launch(void* const* d_in, const int* in_sizes, int n_in,
                              void* d_out, int out_size, void* d_ws, size_t ws_size,
                              hipStream_t stream) {
    const float* x  = (const float*)d_in[0];
    const int*   ei = (const int*)d_in[1];
    const float* W1 = (const float*)d_in[2];
    const float* b1 = (const float*)d_in[3];
    const float* W2 = (const float*)d_in[4];
    const float* b2 = (const float*)d_in[5];
    const float* W3 = (const float*)d_in[6];
    const float* b3 = (const float*)d_in[7];
    float* out = (float*)d_out;

    const int n = in_sizes[0] / 128;   // 100000
    const int e = in_sizes[1] / 2;     // 1600000
    const int* src = ei;
    const int* dst = ei + e;

    // workspace layout (floats)
    float* dinv = (float*)d_ws;          // n
    float* g    = dinv + n;              // n*64
    float* acc  = g + (size_t)n * 64;    // n*64
    float* hbuf = acc + (size_t)n * 64;  // n*64

    const int B = 256;

    // degrees -> dinv
    k_init_deg<<<(n + B - 1) / B, B, 0, stream>>>(dinv, n);
    k_edge_deg<<<(e + B - 1) / B, B, 0, stream>>>(dst, dinv, e);
    k_dinv<<<(n + B - 1) / B, B, 0, stream>>>(dinv, n);

    // ---- layer 1: x[ n x 128 ] @ W1[128x64] ----
    k_gemm_scale<128, 64><<<n / 16, B, 0, stream>>>(x, W1, dinv, g, n);
    hipMemsetAsync(acc, 0, (size_t)n * 64 * sizeof(float), stream);
    k_scatter<64><<<((size_t)e * 64 + B - 1) / B, B, 0, stream>>>(g, src, dst, acc, e);
    k_finalize<64, true><<<(n * 64 + B - 1) / B, B, 0, stream>>>(acc, g, dinv, b1, hbuf, n);

    // ---- layer 2: hbuf[ n x 64 ] @ W2[64x64] ----
    k_gemm_scale<64, 64><<<n / 16, B, 0, stream>>>(hbuf, W2, dinv, g, n);
    hipMemsetAsync(acc, 0, (size_t)n * 64 * sizeof(float), stream);
    k_scatter<64><<<((size_t)e * 64 + B - 1) / B, B, 0, stream>>>(g, src, dst, acc, e);
    k_finalize<64, true><<<(n * 64 + B - 1) / B, B, 0, stream>>>(acc, g, dinv, b2, hbuf, n);

    // ---- layer 3: hbuf[ n x 64 ] @ W3[64x32] -> d_out ----
    k_gemm_scale<64, 32><<<n / 32, B, 0, stream>>>(hbuf, W3, dinv, g, n);
    hipMemsetAsync(acc, 0, (size_t)n * 32 * sizeof(float), stream);
    k_scatter<32><<<((size_t)e * 32 + B - 1) / B, B, 0, stream>>>(g, src, dst, acc, e);
    k_finalize<32, false><<<(n * 32 + B - 1) / B, B, 0, stream>>>(acc, g, dinv, b3, out, n);
}

// Round 2
// 474.686 us; speedup vs baseline: 2.2396x; 2.2396x over previous
//
#include <hip/hip_runtime.h>

// GCN encoder: 3 layers, out = D^-1/2 (A+I) D^-1/2 X W + b, relu between.
// Factored: g = (X W) * dinv[row];  out[d] = dinv[d]*(sum_{s->d} g[s] + g[d]) + b
// Aggregation via CSR (grouped by dst) gather instead of fp32 atomics.

#define SCAN_B 512

__global__ void k_count(const int* __restrict__ dst, int* __restrict__ cnt, int e) {
    int i = blockIdx.x * blockDim.x + threadIdx.x;
    if (i < e) atomicAdd(&cnt[dst[i]], 1);
}

__global__ void k_dinv(const int* __restrict__ cnt, float* __restrict__ dinv, int n) {
    int i = blockIdx.x * blockDim.x + threadIdx.x;
    if (i < n) dinv[i] = 1.0f / sqrtf((float)(cnt[i] + 1));  // +1 self-loop
}

// block-local exclusive scan of cnt -> offs (local), block totals -> bsum
__global__ __launch_bounds__(SCAN_B) void k_scan1(
    const int* __restrict__ cnt, int* __restrict__ offs, int* __restrict__ bsum, int n) {
    __shared__ int s[SCAN_B];
    const int t = threadIdx.x;
    const int i = blockIdx.x * SCAN_B + t;
    int v = (i < n) ? cnt[i] : 0;
    s[t] = v;
    __syncthreads();
    for (int off = 1; off < SCAN_B; off <<= 1) {
        int add = (t >= off) ? s[t - off] : 0;
        __syncthreads();
        s[t] += add;
        __syncthreads();
    }
    if (i < n) offs[i] = s[t] - v;  // exclusive within block
    if (t == SCAN_B - 1) bsum[blockIdx.x] = s[t];
}

// exclusive scan of block sums (nb <= 256), in place
__global__ __launch_bounds__(256) void k_scan2(int* __restrict__ bsum, int nb) {
    __shared__ int s[256];
    const int t = threadIdx.x;
    int v = (t < nb) ? bsum[t] : 0;
    s[t] = v;
    __syncthreads();
    for (int off = 1; off < 256; off <<= 1) {
        int add = (t >= off) ? s[t - off] : 0;
        __syncthreads();
        s[t] += add;
        __syncthreads();
    }
    if (t < nb) bsum[t] = s[t] - v;
}

__global__ __launch_bounds__(256) void k_scan3(
    int* __restrict__ offs, const int* __restrict__ bsum,
    int* __restrict__ cursor, int n) {
    int i = blockIdx.x * 256 + threadIdx.x;
    if (i < n) {
        int v = offs[i] + bsum[i / SCAN_B];
        offs[i] = v;
        cursor[i] = v;
    }
}

// group src indices by dst: esrc[offs[d] ..] = all srcs with that dst
__global__ void k_place(const int* __restrict__ src, const int* __restrict__ dst,
                        int* __restrict__ cursor, int* __restrict__ esrc, int e) {
    int i = blockIdx.x * blockDim.x + threadIdx.x;
    if (i < e) {
        int pos = atomicAdd(&cursor[dst[i]], 1);
        esrc[pos] = src[i];
    }
}

// g[node][f] = dinv[node] * sum_k in[node][k] * W[k][f]
template <int K, int F>
__global__ __launch_bounds__(256) void k_gemm_scale(
    const float* __restrict__ in, const float* __restrict__ W,
    const float* __restrict__ dinv, float* __restrict__ g, int n) {
    constexpr int F4 = F / 4;       // threads per node
    constexpr int T  = 256 / F4;    // nodes per block
    __shared__ float Ws[K * F];
    __shared__ float xs[T][K + 4];
    const int tid = threadIdx.x;

    for (int i = tid; i < K * F; i += 256) Ws[i] = W[i];
    const int node0 = blockIdx.x * T;
    for (int i = tid; i < T * K; i += 256) {
        int r = i / K, c = i % K;
        xs[r][c] = in[(node0 + r) * K + c];
    }
    __syncthreads();

    const int nl = tid / F4;
    const int fq = tid % F4;
    float4 acc = {0.f, 0.f, 0.f, 0.f};
    const float4* Wv = reinterpret_cast<const float4*>(Ws);
#pragma unroll 8
    for (int k = 0; k < K; ++k) {
        float  xv = xs[nl][k];
        float4 w  = Wv[k * F4 + fq];
        acc.x += xv * w.x; acc.y += xv * w.y;
        acc.z += xv * w.z; acc.w += xv * w.w;
    }
    const int node = node0 + nl;
    const float dv = dinv[node];
    float4 r = {acc.x * dv, acc.y * dv, acc.z * dv, acc.w * dv};
    *reinterpret_cast<float4*>(&g[node * F + fq * 4]) = r;
}

// out[d][f] = (relu?)( dinv[d] * (sum_{j in csr[d]} g[esrc[j]][f] + g[d][f]) + b[f] )
template <int F, bool RELU>
__global__ __launch_bounds__(256) void k_aggregate(
    const float* __restrict__ g, const int* __restrict__ offs,
    const int* __restrict__ cnt, const int* __restrict__ esrc,
    const float* __restrict__ dinv, const float* __restrict__ b,
    float* __restrict__ out, int n) {
    constexpr int NPB = 256 / F;    // nodes per block
    const int tid  = threadIdx.x;
    const int node = blockIdx.x * NPB + tid / F;
    const int f    = tid % F;
    if (node >= n) return;
    const int start = offs[node];
    const int end   = start + cnt[node];
    float acc = 0.f;
    int j = start;
    for (; j + 4 <= end; j += 4) {           // 4 gathers in flight
        int s0 = esrc[j], s1 = esrc[j + 1], s2 = esrc[j + 2], s3 = esrc[j + 3];
        acc += g[(size_t)s0 * F + f];
        acc += g[(size_t)s1 * F + f];
        acc += g[(size_t)s2 * F + f];
        acc += g[(size_t)s3 * F + f];
    }
    for (; j < end; ++j) acc += g[(size_t)esrc[j] * F + f];
    acc += g[(size_t)node * F + f];          // self-loop
    float v = dinv[node] * acc + b[f];
    if (RELU) v = fmaxf(v, 0.f);
    out[(size_t)node * F + f] = v;
}

extern "C" void kernel_launch(void* const* d_in, const int* in_sizes, int n_in,
                              void* d_out, int out_size, void* d_ws, size_t ws_size,
                              hipStream_t stream) {
    const float* x  = (const float*)d_in[0];
    const int*   ei = (const int*)d_in[1];
    const float* W1 = (const float*)d_in[2];
    const float* b1 = (const float*)d_in[3];
    const float* W2 = (const float*)d_in[4];
    const float* b2 = (const float*)d_in[5];
    const float* W3 = (const float*)d_in[6];
    const float* b3 = (const float*)d_in[7];
    float* out = (float*)d_out;

    const int n = in_sizes[0] / 128;   // 100000
    const int e = in_sizes[1] / 2;     // 1600000
    const int* src = ei;
    const int* dst = ei + e;

    // workspace layout (4-byte elems)
    float* dinv   = (float*)d_ws;            // n
    float* g      = dinv + n;                // n*64
    float* hbuf   = g + (size_t)n * 64;      // n*64
    int*   cnt    = (int*)(hbuf + (size_t)n * 64);  // n
    int*   offs   = cnt + n;                 // n
    int*   cursor = offs + n;                // n
    int*   bsum   = cursor + n;              // <=512
    int*   esrc   = bsum + 512;              // e

    const int B = 256;
    const int nscan = (n + SCAN_B - 1) / SCAN_B;

    // ---- CSR build (by dst) + dinv ----
    hipMemsetAsync(cnt, 0, (size_t)n * sizeof(int), stream);
    k_count<<<(e + B - 1) / B, B, 0, stream>>>(dst, cnt, e);
    k_dinv<<<(n + B - 1) / B, B, 0, stream>>>(cnt, dinv, n);
    k_scan1<<<nscan, SCAN_B, 0, stream>>>(cnt, offs, bsum, n);
    k_scan2<<<1, 256, 0, stream>>>(bsum, nscan);
    k_scan3<<<(n + B - 1) / B, B, 0, stream>>>(offs, bsum, cursor, n);
    k_place<<<(e + B - 1) / B, B, 0, stream>>>(src, dst, cursor, esrc, e);

    // ---- layer 1: x[n x 128] @ W1[128x64] ----
    k_gemm_scale<128, 64><<<(n + 15) / 16, B, 0, stream>>>(x, W1, dinv, g, n);
    k_aggregate<64, true><<<(n + 3) / 4, B, 0, stream>>>(g, offs, cnt, esrc, dinv, b1, hbuf, n);

    // ---- layer 2: hbuf[n x 64] @ W2[64x64] ----
    k_gemm_scale<64, 64><<<(n + 15) / 16, B, 0, stream>>>(hbuf, W2, dinv, g, n);
    k_aggregate<64, true><<<(n + 3) / 4, B, 0, stream>>>(g, offs, cnt, esrc, dinv, b2, hbuf, n);

    // ---- layer 3: hbuf[n x 64] @ W3[64x32] -> d_out ----
    k_gemm_scale<64, 32><<<(n + 31) / 32, B, 0, stream>>>(hbuf, W3, dinv, g, n);
    k_aggregate<32, false><<<(n + 7) / 8, B, 0, stream>>>(g, offs, cnt, esrc, dinv, b3, out, n);
}

// Round 3
// 387.462 us; speedup vs baseline: 2.7438x; 1.2251x over previous
//
#include <hip/hip_runtime.h>

// GCN encoder: 3 layers, out = D^-1/2 (A+I) D^-1/2 X W + b, relu between.
// Factored: g = (X W) * dinv[row];  out[d] = dinv[d]*(sum_{s->d} g[s] + g[d]) + b
// CSR build: bucket-binned two-pass to avoid scattered-write cacheline blowup.

#define SCAN_B 512
#define BSH 7                    // 128 nodes per bucket
#define BNODES (1 << BSH)
#define NBUCKET_MAX 1024
#define BIN_T 1024
#define BIN_E 13                 // edges per thread in k_bin

__global__ void k_count(const int* __restrict__ dst, int* __restrict__ cnt, int e) {
    int i = blockIdx.x * blockDim.x + threadIdx.x;
    if (i < e) atomicAdd(&cnt[dst[i]], 1);
}

__global__ void k_dinv(const int* __restrict__ cnt, float* __restrict__ dinv, int n) {
    int i = blockIdx.x * blockDim.x + threadIdx.x;
    if (i < n) dinv[i] = 1.0f / sqrtf((float)(cnt[i] + 1));  // +1 self-loop
}

// block-local exclusive scan of cnt -> offs (local), block totals -> bsum
__global__ __launch_bounds__(SCAN_B) void k_scan1(
    const int* __restrict__ cnt, int* __restrict__ offs, int* __restrict__ bsum, int npad) {
    __shared__ int s[SCAN_B];
    const int t = threadIdx.x;
    const int i = blockIdx.x * SCAN_B + t;
    int v = (i < npad) ? cnt[i] : 0;
    s[t] = v;
    __syncthreads();
    for (int off = 1; off < SCAN_B; off <<= 1) {
        int add = (t >= off) ? s[t - off] : 0;
        __syncthreads();
        s[t] += add;
        __syncthreads();
    }
    if (i < npad) offs[i] = s[t] - v;  // exclusive within block
    if (t == SCAN_B - 1) bsum[blockIdx.x] = s[t];
}

// exclusive scan of block sums (nb <= 256), in place
__global__ __launch_bounds__(256) void k_scan2(int* __restrict__ bsum, int nb) {
    __shared__ int s[256];
    const int t = threadIdx.x;
    int v = (t < nb) ? bsum[t] : 0;
    s[t] = v;
    __syncthreads();
    for (int off = 1; off < 256; off <<= 1) {
        int add = (t >= off) ? s[t - off] : 0;
        __syncthreads();
        s[t] += add;
        __syncthreads();
    }
    if (t < nb) bsum[t] = s[t] - v;
}

__global__ __launch_bounds__(256) void k_scan3(
    int* __restrict__ offs, const int* __restrict__ bsum, int npad) {
    int i = blockIdx.x * 256 + threadIdx.x;
    if (i < npad) offs[i] += bsum[i / SCAN_B];
}

// bucket cursors = CSR offset of first node in each bucket (offsets nest)
__global__ void k_binit(const int* __restrict__ offs, int* __restrict__ bcur, int nb) {
    int b = blockIdx.x * blockDim.x + threadIdx.x;
    if (b < nb) bcur[b] = offs[b << BSH];
}

// bin edges into buckets of 128 dst nodes; packed word = (src<<7)|(dst&127).
// Per-block: LDS hist -> one global range reservation per touched bucket ->
// LDS-cursor placement. Each block's ~17 entries per bucket share cachelines.
__global__ __launch_bounds__(BIN_T) void k_bin(
    const int* __restrict__ src, const int* __restrict__ dst,
    int* __restrict__ bcur, unsigned* __restrict__ ebin, int e, int nb) {
    __shared__ int hist[NBUCKET_MAX];
    const int tid = threadIdx.x;
    for (int b = tid; b < nb; b += BIN_T) hist[b] = 0;
    __syncthreads();

    const int base = blockIdx.x * (BIN_T * BIN_E);
    int      bk[BIN_E];
    unsigned pk[BIN_E];
#pragma unroll
    for (int j = 0; j < BIN_E; ++j) {
        int idx = base + j * BIN_T + tid;
        bk[j] = -1;
        if (idx < e) {
            int d = dst[idx], s = src[idx];
            bk[j] = d >> BSH;
            pk[j] = ((unsigned)s << BSH) | (unsigned)(d & (BNODES - 1));
            atomicAdd(&hist[bk[j]], 1);
        }
    }
    __syncthreads();
    for (int b = tid; b < nb; b += BIN_T) {
        int c = hist[b];
        hist[b] = c ? atomicAdd(&bcur[b], c) : 0;   // hist now = running cursor
    }
    __syncthreads();
#pragma unroll
    for (int j = 0; j < BIN_E; ++j) {
        if (bk[j] >= 0) {
            int pos = atomicAdd(&hist[bk[j]], 1);
            ebin[pos] = pk[j];
        }
    }
}

// finish per-node CSR within each bucket; writes stay in the bucket's ~8KB slice
__global__ __launch_bounds__(256) void k_place2(
    const unsigned* __restrict__ ebin, const int* __restrict__ offs,
    int* __restrict__ esrc) {
    __shared__ int cur[BNODES];
    const int b = blockIdx.x, tid = threadIdx.x;
    const int node0 = b << BSH;
    if (tid < BNODES) cur[tid] = offs[node0 + tid];
    __syncthreads();
    const int start = offs[node0];
    const int end   = offs[node0 + BNODES];
    for (int j = start + tid; j < end; j += 256) {
        unsigned p = ebin[j];
        int dl = (int)(p & (BNODES - 1));
        int s  = (int)(p >> BSH);
        int pos = atomicAdd(&cur[dl], 1);
        esrc[pos] = s;
    }
}

// g[node][f] = dinv[node] * sum_k in[node][k] * W[k][f]
template <int K, int F>
__global__ __launch_bounds__(256) void k_gemm_scale(
    const float* __restrict__ in, const float* __restrict__ W,
    const float* __restrict__ dinv, float* __restrict__ g, int n) {
    constexpr int F4 = F / 4;       // threads per node
    constexpr int T  = 256 / F4;    // nodes per block
    __shared__ float Ws[K * F];
    __shared__ float xs[T][K + 4];
    const int tid = threadIdx.x;

    for (int i = tid; i < K * F; i += 256) Ws[i] = W[i];
    const int node0 = blockIdx.x * T;
    for (int i = tid; i < T * K; i += 256) {
        int r = i / K, c = i % K;
        xs[r][c] = in[(node0 + r) * K + c];
    }
    __syncthreads();

    const int nl = tid / F4;
    const int fq = tid % F4;
    float4 acc = {0.f, 0.f, 0.f, 0.f};
    const float4* Wv = reinterpret_cast<const float4*>(Ws);
#pragma unroll 8
    for (int k = 0; k < K; ++k) {
        float  xv = xs[nl][k];
        float4 w  = Wv[k * F4 + fq];
        acc.x += xv * w.x; acc.y += xv * w.y;
        acc.z += xv * w.z; acc.w += xv * w.w;
    }
    const int node = node0 + nl;
    const float dv = dinv[node];
    float4 r = {acc.x * dv, acc.y * dv, acc.z * dv, acc.w * dv};
    *reinterpret_cast<float4*>(&g[node * F + fq * 4]) = r;
}

// out[d][f] = (relu?)( dinv[d] * (sum_{j in csr[d]} g[esrc[j]][f] + g[d][f]) + b[f] )
template <int F, bool RELU>
__global__ __launch_bounds__(256) void k_aggregate(
    const float* __restrict__ g, const int* __restrict__ offs,
    const int* __restrict__ cnt, const int* __restrict__ esrc,
    const float* __restrict__ dinv, const float* __restrict__ b,
    float* __restrict__ out, int n) {
    constexpr int NPB = 256 / F;    // nodes per block
    const int tid  = threadIdx.x;
    const int node = blockIdx.x * NPB + tid / F;
    const int f    = tid % F;
    if (node >= n) return;
    const int start = offs[node];
    const int end   = start + cnt[node];
    float acc = 0.f;
    int j = start;
    for (; j + 4 <= end; j += 4) {
        int s0 = esrc[j], s1 = esrc[j + 1], s2 = esrc[j + 2], s3 = esrc[j + 3];
        acc += g[(size_t)s0 * F + f];
        acc += g[(size_t)s1 * F + f];
        acc += g[(size_t)s2 * F + f];
        acc += g[(size_t)s3 * F + f];
    }
    for (; j < end; ++j) acc += g[(size_t)esrc[j] * F + f];
    acc += g[(size_t)node * F + f];          // self-loop
    float v = dinv[node] * acc + b[f];
    if (RELU) v = fmaxf(v, 0.f);
    out[(size_t)node * F + f] = v;
}

extern "C" void kernel_launch(void* const* d_in, const int* in_sizes, int n_in,
                              void* d_out, int out_size, void* d_ws, size_t ws_size,
                              hipStream_t stream) {
    const float* x  = (const float*)d_in[0];
    const int*   ei = (const int*)d_in[1];
    const float* W1 = (const float*)d_in[2];
    const float* b1 = (const float*)d_in[3];
    const float* W2 = (const float*)d_in[4];
    const float* b2 = (const float*)d_in[5];
    const float* W3 = (const float*)d_in[6];
    const float* b3 = (const float*)d_in[7];
    float* out = (float*)d_out;

    const int n = in_sizes[0] / 128;   // 100000
    const int e = in_sizes[1] / 2;     // 1600000
    const int* src = ei;
    const int* dst = ei + e;

    const int nscan = (n + SCAN_B - 1) / SCAN_B;
    const int npad  = nscan * SCAN_B;           // 100352
    const int nb    = (n + BNODES - 1) >> BSH;  // 782

    // workspace layout (4-byte elems)
    float*    dinv = (float*)d_ws;                   // n
    float*    g    = dinv + n;                       // n*64
    float*    hbuf = g + (size_t)n * 64;             // n*64
    int*      cnt  = (int*)(hbuf + (size_t)n * 64);  // npad
    int*      offs = cnt + npad;                     // npad + pad
    int*      bsum = offs + npad + 8;                // 512
    int*      bcur = bsum + 512;                     // nb
    unsigned* ebin = (unsigned*)(bcur + NBUCKET_MAX);// e
    int*      esrc = (int*)(ebin + e);               // e

    const int B = 256;

    // ---- degree + CSR build ----
    hipMemsetAsync(cnt, 0, (size_t)npad * sizeof(int), stream);
    k_count<<<(e + B - 1) / B, B, 0, stream>>>(dst, cnt, e);
    k_dinv<<<(n + B - 1) / B, B, 0, stream>>>(cnt, dinv, n);
    k_scan1<<<nscan, SCAN_B, 0, stream>>>(cnt, offs, bsum, npad);
    k_scan2<<<1, 256, 0, stream>>>(bsum, nscan);
    k_scan3<<<(npad + B - 1) / B, B, 0, stream>>>(offs, bsum, npad);
    k_binit<<<(nb + B - 1) / B, B, 0, stream>>>(offs, bcur, nb);
    k_bin<<<(e + BIN_T * BIN_E - 1) / (BIN_T * BIN_E), BIN_T, 0, stream>>>(src, dst, bcur, ebin, e, nb);
    k_place2<<<nb, B, 0, stream>>>(ebin, offs, esrc);

    // ---- layer 1: x[n x 128] @ W1[128x64] ----
    k_gemm_scale<128, 64><<<(n + 15) / 16, B, 0, stream>>>(x, W1, dinv, g, n);
    k_aggregate<64, true><<<(n + 3) / 4, B, 0, stream>>>(g, offs, cnt, esrc, dinv, b1, hbuf, n);

    // ---- layer 2: hbuf[n x 64] @ W2[64x64] ----
    k_gemm_scale<64, 64><<<(n + 15) / 16, B, 0, stream>>>(hbuf, W2, dinv, g, n);
    k_aggregate<64, true><<<(n + 3) / 4, B, 0, stream>>>(g, offs, cnt, esrc, dinv, b2, hbuf, n);

    // ---- layer 3: hbuf[n x 64] @ W3[64x32] -> d_out ----
    k_gemm_scale<64, 32><<<(n + 31) / 32, B, 0, stream>>>(hbuf, W3, dinv, g, n);
    k_aggregate<32, false><<<(n + 7) / 8, B, 0, stream>>>(g, offs, cnt, esrc, dinv, b3, out, n);
}

// Round 4
// 308.871 us; speedup vs baseline: 3.4419x; 1.2544x over previous
//
#include <hip/hip_runtime.h>
#include <hip/hip_fp16.h>

// GCN encoder: 3 layers, out = D^-1/2 (A+I) D^-1/2 X W + b, relu between.
// Factored: g = (X W) * dinv[row] stored FP16 (halves gather bytes);
// out[d] = dinv[d]*(sum_{s->d} g[s] + g[d]) + b, accumulation in fp32.
// CSR build: bucket-local throughout (histogram -> 782-scan -> bin -> place),
// per-node counts/offsets/dinv computed inside the bucket pass.

#define BSH 7                    // 128 nodes per bucket
#define BNODES (1 << BSH)
#define NBUCKET_MAX 1024
#define BIN_T 1024
#define BIN_E 13                 // edges per thread in k_bin / k_bcount

// per-block LDS histogram of dst buckets -> global bucket counts
__global__ __launch_bounds__(BIN_T) void k_bcount(
    const int* __restrict__ dst, int* __restrict__ bcnt, int e, int nb) {
    __shared__ int h[NBUCKET_MAX];
    const int tid = threadIdx.x;
    for (int b = tid; b < nb; b += BIN_T) h[b] = 0;
    __syncthreads();
    const int base = blockIdx.x * (BIN_T * BIN_E);
#pragma unroll
    for (int j = 0; j < BIN_E; ++j) {
        int idx = base + j * BIN_T + tid;
        if (idx < e) atomicAdd(&h[dst[idx] >> BSH], 1);
    }
    __syncthreads();
    for (int b = tid; b < nb; b += BIN_T) {
        int c = h[b];
        if (c) atomicAdd(&bcnt[b], c);
    }
}

// single-block exclusive scan of bucket counts -> bobs (nb+1), bcur copy
__global__ __launch_bounds__(1024) void k_bscan(
    const int* __restrict__ bcnt, int* __restrict__ bobs,
    int* __restrict__ bcur, int nb) {
    __shared__ int s[1024];
    const int t = threadIdx.x;
    int v = (t < nb) ? bcnt[t] : 0;
    s[t] = v;
    __syncthreads();
    for (int off = 1; off < 1024; off <<= 1) {
        int add = (t >= off) ? s[t - off] : 0;
        __syncthreads();
        s[t] += add;
        __syncthreads();
    }
    if (t < nb) {
        int excl = s[t] - v;
        bobs[t] = excl;
        bcur[t] = excl;
        if (t == nb - 1) bobs[nb] = s[t];   // total == e
    }
}

// bin edges into buckets of 128 dst nodes; packed word = (src<<7)|(dst&127).
__global__ __launch_bounds__(BIN_T) void k_bin(
    const int* __restrict__ src, const int* __restrict__ dst,
    int* __restrict__ bcur, unsigned* __restrict__ ebin, int e, int nb) {
    __shared__ int hist[NBUCKET_MAX];
    const int tid = threadIdx.x;
    for (int b = tid; b < nb; b += BIN_T) hist[b] = 0;
    __syncthreads();

    const int base = blockIdx.x * (BIN_T * BIN_E);
    int      bk[BIN_E];
    unsigned pk[BIN_E];
#pragma unroll
    for (int j = 0; j < BIN_E; ++j) {
        int idx = base + j * BIN_T + tid;
        bk[j] = -1;
        if (idx < e) {
            int d = dst[idx], s = src[idx];
            bk[j] = d >> BSH;
            pk[j] = ((unsigned)s << BSH) | (unsigned)(d & (BNODES - 1));
            atomicAdd(&hist[bk[j]], 1);
        }
    }
    __syncthreads();
    for (int b = tid; b < nb; b += BIN_T) {
        int c = hist[b];
        hist[b] = c ? atomicAdd(&bcur[b], c) : 0;   // hist now = running cursor
    }
    __syncthreads();
#pragma unroll
    for (int j = 0; j < BIN_E; ++j) {
        if (bk[j] >= 0) {
            int pos = atomicAdd(&hist[bk[j]], 1);
            ebin[pos] = pk[j];
        }
    }
}

// per bucket: LDS node-histogram + 128-scan -> per-node cnt/offs/dinv,
// then place srcs into per-node CSR slots (writes stay in bucket slice).
__global__ __launch_bounds__(256) void k_place2(
    const unsigned* __restrict__ ebin, const int* __restrict__ bobs,
    int* __restrict__ esrc, int* __restrict__ cnt, int* __restrict__ offs,
    float* __restrict__ dinv, int n) {
    __shared__ int hist[BNODES];
    __shared__ int loff[BNODES];
    __shared__ int cur[BNODES];
    const int b = blockIdx.x, tid = threadIdx.x;
    const int node0 = b << BSH;
    const int start = bobs[b];
    const int end   = bobs[b + 1];
    if (tid < BNODES) hist[tid] = 0;
    __syncthreads();
    for (int j = start + tid; j < end; j += 256)
        atomicAdd(&hist[ebin[j] & (BNODES - 1)], 1);
    __syncthreads();
    int v = (tid < BNODES) ? hist[tid] : 0;
    if (tid < BNODES) loff[tid] = v;
    __syncthreads();
    for (int off = 1; off < BNODES; off <<= 1) {
        int add = (tid < BNODES && tid >= off) ? loff[tid - off] : 0;
        __syncthreads();
        if (tid < BNODES) loff[tid] += add;
        __syncthreads();
    }
    if (tid < BNODES) {
        int o = start + loff[tid] - v;   // exclusive
        cur[tid] = o;
        int node = node0 + tid;
        if (node < n) {
            cnt[node]  = v;
            offs[node] = o;
            dinv[node] = rsqrtf((float)(v + 1));  // +1 self-loop
        }
    }
    __syncthreads();
    for (int j = start + tid; j < end; j += 256) {
        unsigned p = ebin[j];
        int pos = atomicAdd(&cur[p & (BNODES - 1)], 1);
        esrc[pos] = (int)(p >> BSH);
    }
}

// g[node][f] = fp16( dinv[node] * sum_k in[node][k] * W[k][f] )
template <int K, int F>
__global__ __launch_bounds__(256) void k_gemm_scale(
    const float* __restrict__ in, const float* __restrict__ W,
    const float* __restrict__ dinv, __half* __restrict__ g, int n) {
    constexpr int F4 = F / 4;       // threads per node
    constexpr int T  = 256 / F4;    // nodes per block
    __shared__ float Ws[K * F];
    __shared__ float xs[T][K + 4];
    const int tid = threadIdx.x;

    for (int i = tid; i < K * F; i += 256) Ws[i] = W[i];
    const int node0 = blockIdx.x * T;
    for (int i = tid; i < T * K; i += 256) {
        int r = i / K, c = i % K;
        xs[r][c] = in[(node0 + r) * K + c];
    }
    __syncthreads();

    const int nl = tid / F4;
    const int fq = tid % F4;
    float4 acc = {0.f, 0.f, 0.f, 0.f};
    const float4* Wv = reinterpret_cast<const float4*>(Ws);
#pragma unroll 8
    for (int k = 0; k < K; ++k) {
        float  xv = xs[nl][k];
        float4 w  = Wv[k * F4 + fq];
        acc.x += xv * w.x; acc.y += xv * w.y;
        acc.z += xv * w.z; acc.w += xv * w.w;
    }
    const int node = node0 + nl;
    const float dv = dinv[node];
    union { __half2 h2[2]; uint2 u; } pk;
    pk.h2[0] = __floats2half2_rn(acc.x * dv, acc.y * dv);
    pk.h2[1] = __floats2half2_rn(acc.z * dv, acc.w * dv);
    *reinterpret_cast<uint2*>(&g[(size_t)node * F + fq * 4]) = pk.u;
}

// out[d][f] = (relu?)( dinv[d] * (sum_{j in csr[d]} g[esrc[j]][f] + g[d][f]) + b[f] )
template <int F, bool RELU>
__global__ __launch_bounds__(256) void k_aggregate(
    const __half* __restrict__ g, const int* __restrict__ offs,
    const int* __restrict__ cnt, const int* __restrict__ esrc,
    const float* __restrict__ dinv, const float* __restrict__ b,
    float* __restrict__ out, int n) {
    constexpr int NPB = 256 / F;    // nodes per block
    const int tid  = threadIdx.x;
    const int node = blockIdx.x * NPB + tid / F;
    const int f    = tid % F;
    if (node >= n) return;
    const int start = offs[node];
    const int end   = start + cnt[node];
    float acc = 0.f;
    int j = start;
    for (; j + 4 <= end; j += 4) {           // 4 gathers in flight
        int s0 = esrc[j], s1 = esrc[j + 1], s2 = esrc[j + 2], s3 = esrc[j + 3];
        float v0 = __half2float(g[(size_t)s0 * F + f]);
        float v1 = __half2float(g[(size_t)s1 * F + f]);
        float v2 = __half2float(g[(size_t)s2 * F + f]);
        float v3 = __half2float(g[(size_t)s3 * F + f]);
        acc += v0 + v1 + v2 + v3;
    }
    for (; j < end; ++j) acc += __half2float(g[(size_t)esrc[j] * F + f]);
    acc += __half2float(g[(size_t)node * F + f]);   // self-loop
    float v = dinv[node] * acc + b[f];
    if (RELU) v = fmaxf(v, 0.f);
    out[(size_t)node * F + f] = v;
}

extern "C" void kernel_launch(void* const* d_in, const int* in_sizes, int n_in,
                              void* d_out, int out_size, void* d_ws, size_t ws_size,
                              hipStream_t stream) {
    const float* x  = (const float*)d_in[0];
    const int*   ei = (const int*)d_in[1];
    const float* W1 = (const float*)d_in[2];
    const float* b1 = (const float*)d_in[3];
    const float* W2 = (const float*)d_in[4];
    const float* b2 = (const float*)d_in[5];
    const float* W3 = (const float*)d_in[6];
    const float* b3 = (const float*)d_in[7];
    float* out = (float*)d_out;

    const int n = in_sizes[0] / 128;   // 100000
    const int e = in_sizes[1] / 2;     // 1600000
    const int* src = ei;
    const int* dst = ei + e;

    const int nb = (n + BNODES - 1) >> BSH;  // 782

    // workspace layout (4-byte units)
    float*    dinv = (float*)d_ws;                    // n
    __half*   g    = (__half*)(dinv + n);             // n*64 halves = n*32 words
    float*    hbuf = (float*)((int*)d_ws + n + (size_t)n * 32);  // n*64
    int*      cnt  = (int*)(hbuf + (size_t)n * 64);   // n
    int*      offs = cnt + n;                         // n
    int*      bcnt = offs + n;                        // NBUCKET_MAX
    int*      bobs = bcnt + NBUCKET_MAX;              // NBUCKET_MAX+1
    int*      bcur = bobs + NBUCKET_MAX + 1;          // NBUCKET_MAX
    unsigned* ebin = (unsigned*)(bcur + NBUCKET_MAX); // e
    int*      esrc = (int*)(ebin + e);                // e

    const int B = 256;
    const int binGrid = (e + BIN_T * BIN_E - 1) / (BIN_T * BIN_E);

    // ---- CSR build (bucket-local), emits cnt/offs/dinv as by-product ----
    hipMemsetAsync(bcnt, 0, NBUCKET_MAX * sizeof(int), stream);
    k_bcount<<<binGrid, BIN_T, 0, stream>>>(dst, bcnt, e, nb);
    k_bscan<<<1, 1024, 0, stream>>>(bcnt, bobs, bcur, nb);
    k_bin<<<binGrid, BIN_T, 0, stream>>>(src, dst, bcur, ebin, e, nb);
    k_place2<<<nb, B, 0, stream>>>(ebin, bobs, esrc, cnt, offs, dinv, n);

    // ---- layer 1: x[n x 128] @ W1[128x64] ----
    k_gemm_scale<128, 64><<<(n + 15) / 16, B, 0, stream>>>(x, W1, dinv, g, n);
    k_aggregate<64, true><<<(n + 3) / 4, B, 0, stream>>>(g, offs, cnt, esrc, dinv, b1, hbuf, n);

    // ---- layer 2: hbuf[n x 64] @ W2[64x64] ----
    k_gemm_scale<64, 64><<<(n + 15) / 16, B, 0, stream>>>(hbuf, W2, dinv, g, n);
    k_aggregate<64, true><<<(n + 3) / 4, B, 0, stream>>>(g, offs, cnt, esrc, dinv, b2, hbuf, n);

    // ---- layer 3: hbuf[n x 64] @ W3[64x32] -> d_out ----
    k_gemm_scale<64, 32><<<(n + 31) / 32, B, 0, stream>>>(hbuf, W3, dinv, g, n);
    k_aggregate<32, false><<<(n + 7) / 8, B, 0, stream>>>(g, offs, cnt, esrc, dinv, b3, out, n);
}

// Round 5
// 271.578 us; speedup vs baseline: 3.9145x; 1.1373x over previous
//
#include <hip/hip_runtime.h>
#include <hip/hip_fp16.h>

// GCN encoder: 3 layers, out = D^-1/2 (A+I) D^-1/2 X W + b, relu between.
// g = (X W) * dinv[row] stored FP16; out[d] = dinv[d]*(sum g[s] + g[d]) + b.
// Aggregate: lane=(edge-subgroup, f-slice) so each wave instruction gathers
// 512B across 4-8 edges; shfl_xor butterfly combines subgroups.
// CSR build: fixed-capacity buckets (4096 >= 2x Poisson mean), no scan needed.

#define BSH 7                    // 128 nodes per bucket
#define BNODES (1 << BSH)
#define NBUCKET_MAX 1024
#define CAPSH 12                 // 4096 edge slots per bucket
#define BIN_T 1024
#define BIN_E 4                  // edges per thread in k_bin

__global__ void k_binit0(int* __restrict__ bcur, int nb) {
    int b = blockIdx.x * blockDim.x + threadIdx.x;
    if (b < nb) bcur[b] = b << CAPSH;
}

// bin edges into buckets of 128 dst nodes; packed word = (src<<7)|(dst&127).
__global__ __launch_bounds__(BIN_T) void k_bin(
    const int* __restrict__ src, const int* __restrict__ dst,
    int* __restrict__ bcur, unsigned* __restrict__ ebin, int e, int nb) {
    __shared__ int hist[NBUCKET_MAX];
    const int tid = threadIdx.x;
    for (int b = tid; b < nb; b += BIN_T) hist[b] = 0;
    __syncthreads();

    const int base = blockIdx.x * (BIN_T * BIN_E);
    int      bk[BIN_E];
    unsigned pk[BIN_E];
#pragma unroll
    for (int j = 0; j < BIN_E; ++j) {
        int idx = base + j * BIN_T + tid;
        bk[j] = -1;
        if (idx < e) {
            int d = dst[idx], s = src[idx];
            bk[j] = d >> BSH;
            pk[j] = ((unsigned)s << BSH) | (unsigned)(d & (BNODES - 1));
            atomicAdd(&hist[bk[j]], 1);
        }
    }
    __syncthreads();
    for (int b = tid; b < nb; b += BIN_T) {
        int c = hist[b];
        hist[b] = c ? atomicAdd(&bcur[b], c) : 0;   // hist now = running cursor
    }
    __syncthreads();
#pragma unroll
    for (int j = 0; j < BIN_E; ++j) {
        if (bk[j] >= 0) {
            int pos = atomicAdd(&hist[bk[j]], 1);
            ebin[pos] = pk[j];
        }
    }
}

// per bucket: LDS node-histogram + 128-scan -> per-node cnt/offs/dinv
// (bucket-strided offsets), then place srcs into per-node CSR slots.
__global__ __launch_bounds__(256) void k_place2(
    const unsigned* __restrict__ ebin, const int* __restrict__ bcur,
    int* __restrict__ esrc, int* __restrict__ cnt, int* __restrict__ offs,
    float* __restrict__ dinv, int n) {
    __shared__ int hist[BNODES];
    __shared__ int loff[BNODES];
    __shared__ int cur[BNODES];
    const int b = blockIdx.x, tid = threadIdx.x;
    const int node0 = b << BSH;
    const int start = b << CAPSH;
    const int end   = bcur[b];
    if (tid < BNODES) hist[tid] = 0;
    __syncthreads();
    for (int j = start + tid; j < end; j += 256)
        atomicAdd(&hist[ebin[j] & (BNODES - 1)], 1);
    __syncthreads();
    int v = (tid < BNODES) ? hist[tid] : 0;
    if (tid < BNODES) loff[tid] = v;
    __syncthreads();
    for (int off = 1; off < BNODES; off <<= 1) {
        int add = (tid < BNODES && tid >= off) ? loff[tid - off] : 0;
        __syncthreads();
        if (tid < BNODES) loff[tid] += add;
        __syncthreads();
    }
    if (tid < BNODES) {
        int o = start + loff[tid] - v;   // exclusive, bucket-strided
        cur[tid] = o;
        int node = node0 + tid;
        if (node < n) {
            cnt[node]  = v;
            offs[node] = o;
            dinv[node] = rsqrtf((float)(v + 1));  // +1 self-loop
        }
    }
    __syncthreads();
    for (int j = start + tid; j < end; j += 256) {
        unsigned p = ebin[j];
        int pos = atomicAdd(&cur[p & (BNODES - 1)], 1);
        esrc[pos] = (int)(p >> BSH);
    }
}

// g[node][f] = fp16( dinv[node] * sum_k in[node][k] * W[k][f] )
template <int K, int F>
__global__ __launch_bounds__(256) void k_gemm_scale(
    const float* __restrict__ in, const float* __restrict__ W,
    const float* __restrict__ dinv, __half* __restrict__ g, int n) {
    constexpr int F4 = F / 4;       // threads per node
    constexpr int T  = 256 / F4;    // nodes per block
    constexpr int KW = K / 4;
    __shared__ float Ws[K * F];
    __shared__ float xs[T][K];      // unpadded: reads are 16-lane broadcasts
    const int tid = threadIdx.x;

    const float4* W4 = reinterpret_cast<const float4*>(W);
    float4* Ws4 = reinterpret_cast<float4*>(Ws);
    for (int i = tid; i < K * F / 4; i += 256) Ws4[i] = W4[i];
    const int node0 = blockIdx.x * T;
    const float4* in4 = reinterpret_cast<const float4*>(in);
    float4* xs4 = reinterpret_cast<float4*>(&xs[0][0]);
    for (int i = tid; i < T * KW; i += 256)
        xs4[i] = in4[(size_t)node0 * KW + i];   // tile is contiguous
    __syncthreads();

    const int nl = tid / F4;
    const int fq = tid % F4;
    float4 acc = {0.f, 0.f, 0.f, 0.f};
    const float4* Wv = reinterpret_cast<const float4*>(Ws);
#pragma unroll 8
    for (int k = 0; k < K; ++k) {
        float  xv = xs[nl][k];
        float4 w  = Wv[k * F4 + fq];
        acc.x += xv * w.x; acc.y += xv * w.y;
        acc.z += xv * w.z; acc.w += xv * w.w;
    }
    const int node = node0 + nl;
    if (node < n) {
        const float dv = dinv[node];
        union { __half2 h2[2]; uint2 u; } pk;
        pk.h2[0] = __floats2half2_rn(acc.x * dv, acc.y * dv);
        pk.h2[1] = __floats2half2_rn(acc.z * dv, acc.w * dv);
        *reinterpret_cast<uint2*>(&g[(size_t)node * F + fq * 4]) = pk.u;
    }
}

__device__ inline float4 h4_to_f4(uint2 u) {
    __half2 a = *reinterpret_cast<__half2*>(&u.x);
    __half2 b = *reinterpret_cast<__half2*>(&u.y);
    float2 fa = __half22float2(a), fb = __half22float2(b);
    return make_float4(fa.x, fa.y, fb.x, fb.y);
}

__device__ inline void red4(float4& a, int mask) {
    a.x += __shfl_xor(a.x, mask);
    a.y += __shfl_xor(a.y, mask);
    a.z += __shfl_xor(a.z, mask);
    a.w += __shfl_xor(a.w, mask);
}

// F: feature width (halves). One node per wave; lane = (edge-subgroup, f-slice).
// EG = 64*4/F subgroups, each lane loads 8B (4 halves) of one edge's row.
template <int F, bool RELU>
__global__ __launch_bounds__(256) void k_agg(
    const __half* __restrict__ g, const int* __restrict__ offs,
    const int* __restrict__ cnt, const int* __restrict__ esrc,
    const float* __restrict__ dinv, const float* __restrict__ b,
    float* __restrict__ out, int n) {
    constexpr int FS = F / 4;          // f-slices per row (lanes per edge)
    constexpr int EG = 64 / FS;        // edge subgroups per wave
    const int wid  = threadIdx.x >> 6;
    const int lane = threadIdx.x & 63;
    const int node = blockIdx.x * 4 + wid;
    if (node >= n) return;
    const int eg = lane / FS;
    const int fs = lane % FS;          // covers halves [fs*4, fs*4+4)
    const int start = offs[node];
    const int m     = cnt[node];
    float4 acc = {0.f, 0.f, 0.f, 0.f};
    int j = 0;
    for (; j + 2 * EG <= m; j += 2 * EG) {   // 2 row-loads in flight per lane
        int s0 = esrc[start + j + eg];
        int s1 = esrc[start + j + EG + eg];
        uint2 u0 = *reinterpret_cast<const uint2*>(g + (size_t)s0 * F + fs * 4);
        uint2 u1 = *reinterpret_cast<const uint2*>(g + (size_t)s1 * F + fs * 4);
        float4 v0 = h4_to_f4(u0), v1 = h4_to_f4(u1);
        acc.x += v0.x + v1.x; acc.y += v0.y + v1.y;
        acc.z += v0.z + v1.z; acc.w += v0.w + v1.w;
    }
    for (; j + EG <= m; j += EG) {
        int s0 = esrc[start + j + eg];
        uint2 u0 = *reinterpret_cast<const uint2*>(g + (size_t)s0 * F + fs * 4);
        float4 v0 = h4_to_f4(u0);
        acc.x += v0.x; acc.y += v0.y; acc.z += v0.z; acc.w += v0.w;
    }
    int rem = m - j;
    if (eg < rem) {
        int s0 = esrc[start + j + eg];
        uint2 u0 = *reinterpret_cast<const uint2*>(g + (size_t)s0 * F + fs * 4);
        float4 v0 = h4_to_f4(u0);
        acc.x += v0.x; acc.y += v0.y; acc.z += v0.z; acc.w += v0.w;
    }
    // butterfly over edge subgroups (lane strides FS, FS*2, ... , 32)
#pragma unroll
    for (int msk = FS; msk < 64; msk <<= 1) red4(acc, msk);
    if (eg == 0) {
        uint2 us = *reinterpret_cast<const uint2*>(g + (size_t)node * F + fs * 4);
        float4 sv = h4_to_f4(us);
        float  dv = dinv[node];
        float4 bv = *reinterpret_cast<const float4*>(b + fs * 4);
        float4 r;
        r.x = dv * (acc.x + sv.x) + bv.x;
        r.y = dv * (acc.y + sv.y) + bv.y;
        r.z = dv * (acc.z + sv.z) + bv.z;
        r.w = dv * (acc.w + sv.w) + bv.w;
        if (RELU) {
            r.x = fmaxf(r.x, 0.f); r.y = fmaxf(r.y, 0.f);
            r.z = fmaxf(r.z, 0.f); r.w = fmaxf(r.w, 0.f);
        }
        *reinterpret_cast<float4*>(out + (size_t)node * F + fs * 4) = r;
    }
}

extern "C" void kernel_launch(void* const* d_in, const int* in_sizes, int n_in,
                              void* d_out, int out_size, void* d_ws, size_t ws_size,
                              hipStream_t stream) {
    const float* x  = (const float*)d_in[0];
    const int*   ei = (const int*)d_in[1];
    const float* W1 = (const float*)d_in[2];
    const float* b1 = (const float*)d_in[3];
    const float* W2 = (const float*)d_in[4];
    const float* b2 = (const float*)d_in[5];
    const float* W3 = (const float*)d_in[6];
    const float* b3 = (const float*)d_in[7];
    float* out = (float*)d_out;

    const int n = in_sizes[0] / 128;   // 100000
    const int e = in_sizes[1] / 2;     // 1600000
    const int* src = ei;
    const int* dst = ei + e;

    const int nb = (n + BNODES - 1) >> BSH;  // 782

    // workspace layout (4-byte units)
    float*    dinv = (float*)d_ws;                     // n
    __half*   g    = (__half*)(dinv + n);              // n*64 halves
    float*    hbuf = (float*)((int*)d_ws + n + (size_t)n * 32);  // n*64
    int*      cnt  = (int*)(hbuf + (size_t)n * 64);    // n
    int*      offs = cnt + n;                          // n
    int*      bcur = offs + n;                         // NBUCKET_MAX
    unsigned* ebin = (unsigned*)(bcur + NBUCKET_MAX);  // nb<<CAPSH
    int*      esrc = (int*)(ebin + ((size_t)nb << CAPSH));  // nb<<CAPSH

    const int B = 256;
    const int binGrid = (e + BIN_T * BIN_E - 1) / (BIN_T * BIN_E);

    // ---- CSR build (fixed-capacity buckets; emits cnt/offs/dinv) ----
    k_binit0<<<(nb + B - 1) / B, B, 0, stream>>>(bcur, nb);
    k_bin<<<binGrid, BIN_T, 0, stream>>>(src, dst, bcur, ebin, e, nb);
    k_place2<<<nb, B, 0, stream>>>(ebin, bcur, esrc, cnt, offs, dinv, n);

    // ---- layer 1: x[n x 128] @ W1[128x64] ----
    k_gemm_scale<128, 64><<<(n + 15) / 16, B, 0, stream>>>(x, W1, dinv, g, n);
    k_agg<64, true><<<(n + 3) / 4, B, 0, stream>>>(g, offs, cnt, esrc, dinv, b1, hbuf, n);

    // ---- layer 2: hbuf[n x 64] @ W2[64x64] ----
    k_gemm_scale<64, 64><<<(n + 15) / 16, B, 0, stream>>>(hbuf, W2, dinv, g, n);
    k_agg<64, true><<<(n + 3) / 4, B, 0, stream>>>(g, offs, cnt, esrc, dinv, b2, hbuf, n);

    // ---- layer 3: hbuf[n x 64] @ W3[64x32] -> d_out ----
    k_gemm_scale<64, 32><<<(n + 31) / 32, B, 0, stream>>>(hbuf, W3, dinv, g, n);
    k_agg<32, false><<<(n + 3) / 4, B, 0, stream>>>(g, offs, cnt, esrc, dinv, b3, out, n);
}